// Round 8
// baseline (608.294 us; speedup 1.0000x reference)
//
#include <hip/hip_runtime.h>

#define N_NODES 100000
#define N_EDGES 1600000
#define N_GRAPHS 2048
#define DIM 128

// bucket CSR build params
#define NBUK 196      // ceil(100000/512)
#define BUKSH 9       // bucket = dst >> 9 (512 nodes per bucket)
#define NCH 256       // edge chunks (blocks) in passes A/C
#define EPB 6250      // edges per chunk = N_EDGES / NCH
#define NMAT (NBUK * NCH)  // 50176

// degree counting-sort params
#define NDB 98        // node chunks (1024 nodes each)
#define DBINS 64
#define DMAT (DBINS * NDB)  // 6272

typedef short short8v __attribute__((ext_vector_type(8)));
typedef float float4v __attribute__((ext_vector_type(4)));
typedef float float2v __attribute__((ext_vector_type(2)));

__device__ __forceinline__ unsigned short f2bf(float f) {
  union { float f; unsigned u; } x; x.f = f;
  unsigned r = x.u + 0x7fffu + ((x.u >> 16) & 1u);
  return (unsigned short)(r >> 16);
}
__device__ __forceinline__ float bfhi2f(unsigned bits) {  // bits already in high half
  union { unsigned u; float f; } x; x.u = bits; return x.f;
}
__device__ __forceinline__ void accum8(float* p, uint4 v) {
  p[0] += bfhi2f(v.x << 16); p[1] += bfhi2f(v.x & 0xffff0000u);
  p[2] += bfhi2f(v.y << 16); p[3] += bfhi2f(v.y & 0xffff0000u);
  p[4] += bfhi2f(v.z << 16); p[5] += bfhi2f(v.z & 0xffff0000u);
  p[6] += bfhi2f(v.w << 16); p[7] += bfhi2f(v.w & 0xffff0000u);
}
// packed-pair version: two adds per uint fuse into v_pk_add_f32
__device__ __forceinline__ void accum8pk(float2v* p, uint4 v) {
  float2v t;
  t[0] = bfhi2f(v.x << 16); t[1] = bfhi2f(v.x & 0xffff0000u); p[0] += t;
  t[0] = bfhi2f(v.y << 16); t[1] = bfhi2f(v.y & 0xffff0000u); p[1] += t;
  t[0] = bfhi2f(v.z << 16); t[1] = bfhi2f(v.z & 0xffff0000u); p[2] += t;
  t[0] = bfhi2f(v.w << 16); t[1] = bfhi2f(v.w & 0xffff0000u); p[3] += t;
}

// ---------------- bucket CSR build (zero global atomics) ----------------
__global__ __launch_bounds__(256) void k_bcount(const int* __restrict__ dst, int* __restrict__ cntmat) {
  __shared__ int cnt[NBUK];
  int b = blockIdx.x, t = threadIdx.x;
  if (t < NBUK) cnt[t] = 0;
  __syncthreads();
  int e0 = b * EPB;
  for (int j = t; j < EPB; j += 256) atomicAdd(&cnt[dst[e0 + j] >> BUKSH], 1);
  __syncthreads();
  if (t < NBUK) cntmat[t * NCH + b] = cnt[t];
}

// generic scan (chunk = 1024/block)
__global__ __launch_bounds__(256) void k_scan1g(const int* __restrict__ in, int n,
                                                int* __restrict__ tmp, int* __restrict__ bsum) {
  __shared__ int sh[256];
  int b = blockIdx.x, t = threadIdx.x;
  int base = b * 1024 + t * 4;
  int v[4], s = 0;
#pragma unroll
  for (int i = 0; i < 4; i++) { v[i] = (base + i < n) ? in[base + i] : 0; s += v[i]; }
  sh[t] = s;
  __syncthreads();
  for (int off = 1; off < 256; off <<= 1) {
    int x = (t >= off) ? sh[t - off] : 0;
    __syncthreads();
    sh[t] += x;
    __syncthreads();
  }
  int run = sh[t] - s;
#pragma unroll
  for (int i = 0; i < 4; i++) { run += v[i]; if (base + i < n) tmp[base + i] = run; }
  if (t == 255) bsum[b] = sh[255];
}

__global__ void k_scan2g(int* __restrict__ bsum, int nb) {
  __shared__ int sh[128];
  int t = threadIdx.x;
  int v = (t < nb) ? bsum[t] : 0;
  sh[t] = v;
  __syncthreads();
  for (int off = 1; off < 128; off <<= 1) {
    int x = (t >= off) ? sh[t - off] : 0;
    __syncthreads();
    sh[t] += x;
    __syncthreads();
  }
  if (t < nb) bsum[t] = sh[t] - v;  // exclusive
}

__global__ __launch_bounds__(256) void k_exc(const int* __restrict__ tmp, const int* __restrict__ bsum,
                                             const int* __restrict__ in, int n, int* __restrict__ outExc) {
  int i = blockIdx.x * 256 + threadIdx.x;
  if (i < n) outExc[i] = tmp[i] + bsum[i >> 10] - in[i];
}

__global__ __launch_bounds__(256) void k_bscatter(const int* __restrict__ src, const int* __restrict__ dst,
                                                  const int* __restrict__ base, int2* __restrict__ epk) {
  __shared__ int cur[NBUK];
  int b = blockIdx.x, t = threadIdx.x;
  if (t < NBUK) cur[t] = base[t * NCH + b];
  __syncthreads();
  int e0 = b * EPB;
  for (int j = t; j < EPB; j += 256) {
    int s = src[e0 + j], d = dst[e0 + j];
    int pos = atomicAdd(&cur[d >> BUKSH], 1);
    epk[pos] = make_int2(s, d);
  }
}

__global__ __launch_bounds__(256) void k_bfinish(const int2* __restrict__ epk, const int* __restrict__ base,
                                                 int* __restrict__ rowptr, int* __restrict__ col) {
  __shared__ int a[512];
  __shared__ int sh[256];
  int k = blockIdx.x, t = threadIdx.x;
  int bstart = base[k * NCH];
  int bend = (k + 1 < NBUK) ? base[(k + 1) * NCH] : N_EDGES;
  a[t] = 0; a[t + 256] = 0;
  __syncthreads();
  for (int i = bstart + t; i < bend; i += 256) atomicAdd(&a[epk[i].y - (k << BUKSH)], 1);
  __syncthreads();
  int c0 = a[2 * t], c1 = a[2 * t + 1];
  int s = c0 + c1;
  sh[t] = s;
  __syncthreads();
  for (int off = 1; off < 256; off <<= 1) {
    int x = (t >= off) ? sh[t - off] : 0;
    __syncthreads();
    sh[t] += x;
    __syncthreads();
  }
  int excl = sh[t] - s;
  int st0 = bstart + excl;
  int st1 = st0 + c0;
  int g0 = (k << BUKSH) + 2 * t, g1 = g0 + 1;
  if (g0 < N_NODES) rowptr[g0] = st0;
  if (g1 < N_NODES) rowptr[g1] = st1;
  if (k == NBUK - 1 && t == 0) rowptr[N_NODES] = N_EDGES;
  __syncthreads();
  a[2 * t] = st0; a[2 * t + 1] = st1;  // convert to cursors
  __syncthreads();
  for (int i = bstart + t; i < bend; i += 256) {
    int2 e = epk[i];
    int pos = atomicAdd(&a[e.y - (k << BUKSH)], 1);
    col[pos] = e.x;
  }
}

// ---------------- degree counting sort (load balance for k_agg) ----------------
__global__ __launch_bounds__(256) void k_dcnt(const int* __restrict__ rowptr, int* __restrict__ dcnt) {
  __shared__ int h[DBINS];
  int b = blockIdx.x, t = threadIdx.x;
  if (t < DBINS) h[t] = 0;
  __syncthreads();
  int base = b * 1024;
  for (int j = t; j < 1024; j += 256) {
    int n = base + j;
    if (n < N_NODES) {
      int d = rowptr[n + 1] - rowptr[n];
      atomicAdd(&h[d > 63 ? 63 : d], 1);
    }
  }
  __syncthreads();
  if (t < DBINS) dcnt[t * NDB + b] = h[t];
}

__global__ __launch_bounds__(256) void k_dscatter(const int* __restrict__ rowptr,
                                                  const int* __restrict__ dbase, int* __restrict__ order) {
  __shared__ int cur[DBINS];
  int b = blockIdx.x, t = threadIdx.x;
  if (t < DBINS) cur[t] = dbase[t * NDB + b];
  __syncthreads();
  int base = b * 1024;
  for (int j = t; j < 1024; j += 256) {
    int n = base + j;
    if (n < N_NODES) {
      int d = rowptr[n + 1] - rowptr[n];
      int pos = atomicAdd(&cur[d > 63 ? 63 : d], 1);
      order[pos] = n;
    }
  }
}

// ---------------- graph boundary pointers (batch is sorted) ----------------
__global__ __launch_bounds__(256) void k_gptr(const int* __restrict__ batch, int* __restrict__ gptr) {
  int i = blockIdx.x * 256 + threadIdx.x;
  if (i >= N_NODES) return;
  int b = batch[i];
  int a = (i == 0) ? -1 : batch[i - 1];
  for (int g = a + 1; g <= b; g++) gptr[g] = i;
  if (i == N_NODES - 1) {
    for (int g = b + 1; g <= N_GRAPHS; g++) gptr[g] = N_NODES;
  }
}

// ---------------- dtype converts ----------------
__global__ __launch_bounds__(256) void k_cvtx(const float* __restrict__ x, unsigned short* __restrict__ h) {
  int i = blockIdx.x * 256 + threadIdx.x;  // over N*DIM/4
  if (i < N_NODES * DIM / 4) {
    float4 v = ((const float4*)x)[i];
    unsigned lo = (unsigned)f2bf(v.x) | ((unsigned)f2bf(v.y) << 16);
    unsigned hi = (unsigned)f2bf(v.z) | ((unsigned)f2bf(v.w) << 16);
    ((uint2*)h)[i] = make_uint2(lo, hi);
  }
}

// Weights -> bf16 MFMA B-fragment order.
__global__ __launch_bounds__(256) void k_cvtw(const float* w0, const float* w1, const float* w2, const float* w3,
                                              const float* w4, const float* w5, const float* w6, const float* w7,
                                              unsigned short* __restrict__ wbF) {
  int i = blockIdx.x * 256 + threadIdx.x;
  if (i < 4 * 8 * 8 * 64 * 8) {
    int j = i & 7, l = (i >> 3) & 63, c = (i >> 9) & 7, kc = (i >> 12) & 7, layer = i >> 15;
    int m = layer * 2 + (kc >> 2);
    const float* w;
    switch (m) {
      case 0: w = w0; break; case 1: w = w1; break; case 2: w = w2; break; case 3: w = w3; break;
      case 4: w = w4; break; case 5: w = w5; break; case 6: w = w6; break; default: w = w7; break;
    }
    int kin = (kc & 3) * 32 + ((l >> 4) * 8) + j;
    int n = c * 16 + (l & 15);
    wbF[i] = f2bf(w[kin * 128 + n]);
  }
}

// ---------------- aggregation: wave per node (degree-sorted order), dwordx4 gathers ----------------
__global__ __launch_bounds__(256) void k_agg(const int* __restrict__ order, const int* __restrict__ rowptr,
                                             const int* __restrict__ col,
                                             const unsigned short* __restrict__ hIn,
                                             unsigned short* __restrict__ aggOut) {
  int widx = blockIdx.x * 4 + (threadIdx.x >> 6);
  if (widx >= N_NODES) return;
  int node = order[widx];
  int lane = threadIdx.x & 63;
  int sub = lane >> 4;
  int li = lane & 15;
  int s0 = rowptr[node], s1 = rowptr[node + 1];
  float2v p[4];
#pragma unroll
  for (int j = 0; j < 4; j++) { p[j][0] = 0.f; p[j][1] = 0.f; }

  int e = s0;
  for (; e + 16 <= s1; e += 16) {
    int c0 = col[e + sub];
    int c1 = col[e + 4 + sub];
    int c2 = col[e + 8 + sub];
    int c3 = col[e + 12 + sub];
    uint4 v0 = *(const uint4*)(hIn + (size_t)c0 * DIM + li * 8);
    uint4 v1 = *(const uint4*)(hIn + (size_t)c1 * DIM + li * 8);
    uint4 v2 = *(const uint4*)(hIn + (size_t)c2 * DIM + li * 8);
    uint4 v3 = *(const uint4*)(hIn + (size_t)c3 * DIM + li * 8);
    accum8pk(p, v0);
    accum8pk(p, v1);
    accum8pk(p, v2);
    accum8pk(p, v3);
  }
  if (e + 8 <= s1) {
    int c0 = col[e + sub];
    int c1 = col[e + 4 + sub];
    uint4 v0 = *(const uint4*)(hIn + (size_t)c0 * DIM + li * 8);
    uint4 v1 = *(const uint4*)(hIn + (size_t)c1 * DIM + li * 8);
    accum8pk(p, v0);
    accum8pk(p, v1);
    e += 8;
  }
  if (e + 4 <= s1) {
    int c0 = col[e + sub];
    uint4 v0 = *(const uint4*)(hIn + (size_t)c0 * DIM + li * 8);
    accum8pk(p, v0);
    e += 4;
  }
  if (e + sub < s1) {
    int c0 = col[e + sub];
    uint4 v0 = *(const uint4*)(hIn + (size_t)c0 * DIM + li * 8);
    accum8pk(p, v0);
  }

#pragma unroll
  for (int j = 0; j < 4; j++) {
#pragma unroll
    for (int q = 0; q < 2; q++) {
      p[j][q] += __shfl_xor(p[j][q], 16, 64);
      p[j][q] += __shfl_xor(p[j][q], 32, 64);
    }
  }

  if (sub == 0) {
    uint4 o;
    o.x = (unsigned)f2bf(p[0][0]) | ((unsigned)f2bf(p[0][1]) << 16);
    o.y = (unsigned)f2bf(p[1][0]) | ((unsigned)f2bf(p[1][1]) << 16);
    o.z = (unsigned)f2bf(p[2][0]) | ((unsigned)f2bf(p[2][1]) << 16);
    o.w = (unsigned)f2bf(p[3][0]) | ((unsigned)f2bf(p[3][1]) << 16);
    *(uint4*)(aggOut + (size_t)node * DIM + li * 8) = o;
  }
}

// ---------------- fused conv GEMM: h' = relu(agg@Wrel + h@Wroot + b) ----------------
__global__ __launch_bounds__(256) void k_conv(const unsigned short* __restrict__ aggB,
                                              const unsigned short* __restrict__ hIn,
                                              const unsigned short* __restrict__ wbF,
                                              const float* __restrict__ bias,
                                              unsigned short* __restrict__ hOut) {
  __shared__ uint4 As[4096];  // 64 KB
  const int t = threadIdx.x;
  const int row0b = blockIdx.x * 128;

#pragma unroll
  for (int j = 0; j < 8; j++) {
    int r = j * 16 + (t >> 4);
    int c = t & 15;
    int rsrc = row0b + r; if (rsrc > N_NODES - 1) rsrc = N_NODES - 1;
    uint4 v = *(const uint4*)(aggB + (size_t)rsrc * DIM + c * 8);
    As[((r >> 4) * 32 + c) * 16 + ((r & 15) ^ c)] = v;
  }
#pragma unroll
  for (int j = 0; j < 8; j++) {
    int r = j * 16 + (t >> 4);
    int c = t & 15;
    int rsrc = row0b + r; if (rsrc > N_NODES - 1) rsrc = N_NODES - 1;
    uint4 v = *(const uint4*)(hIn + (size_t)rsrc * DIM + c * 8);
    As[((r >> 4) * 32 + 16 + c) * 16 + ((r & 15) ^ c)] = v;
  }
  __syncthreads();

  const int wave = t >> 6, lane = t & 63;
  const int row0 = row0b + wave * 32;

  float4v acc[2][8];
#pragma unroll
  for (int r = 0; r < 2; r++)
#pragma unroll
    for (int c = 0; c < 8; c++)
#pragma unroll
      for (int i = 0; i < 4; i++) acc[r][c][i] = 0.f;

#pragma unroll
  for (int kc = 0; kc < 8; kc++) {
    short8v afr[2];
#pragma unroll
    for (int r = 0; r < 2; r++) {
      int g = wave * 2 + r;
      int c = kc * 4 + (lane >> 4);
      int rr = (lane & 15) ^ (c & 15);
      afr[r] = *(const short8v*)&As[(g * 32 + c) * 16 + rr];
    }
#pragma unroll
    for (int c = 0; c < 8; c++) {
      short8v bfr = *(const short8v*)(wbF + (size_t)((kc * 8 + c) * 64 + lane) * 8);
#pragma unroll
      for (int r = 0; r < 2; r++)
        acc[r][c] = __builtin_amdgcn_mfma_f32_16x16x32_bf16(afr[r], bfr, acc[r][c], 0, 0, 0);
    }
  }

#pragma unroll
  for (int r = 0; r < 2; r++) {
    int rbase = row0 + r * 16 + (lane >> 4) * 4;
#pragma unroll
    for (int c = 0; c < 8; c++) {
      int colidx = c * 16 + (lane & 15);
      float bv = bias[colidx];
#pragma unroll
      for (int i = 0; i < 4; i++) {
        int row = rbase + i;
        if (row < N_NODES) {
          float v = acc[r][c][i] + bv;
          v = v > 0.f ? v : 0.f;
          hOut[row * DIM + colidx] = f2bf(v);
        }
      }
    }
  }
}

// ---------------- pooling: one wave per graph, flat uint4 streaming, no atomics ----------------
__global__ __launch_bounds__(256) void k_pool(const unsigned short* __restrict__ h,
                                              const int* __restrict__ gptr,
                                              float* __restrict__ pooledMean) {
  int g = blockIdx.x * 4 + (threadIdx.x >> 6);
  if (g >= N_GRAPHS) return;
  int lane = threadIdx.x & 63;
  int li = lane & 15;
  int s0 = gptr[g], s1 = gptr[g + 1];
  float p[8];
#pragma unroll
  for (int j = 0; j < 8; j++) p[j] = 0.f;
  int f1 = s1 * 16;
  for (int f = s0 * 16 + lane; f < f1; f += 64) {
    uint4 v = ((const uint4*)h)[f];
    accum8(p, v);
  }
#pragma unroll
  for (int j = 0; j < 8; j++) {
    p[j] += __shfl_xor(p[j], 16, 64);
    p[j] += __shfl_xor(p[j], 32, 64);
  }
  float inv = (s1 > s0) ? 1.f / (float)(s1 - s0) : 0.f;
  if (lane < 16) {
    float4 o0 = make_float4(p[0] * inv, p[1] * inv, p[2] * inv, p[3] * inv);
    float4 o1 = make_float4(p[4] * inv, p[5] * inv, p[6] * inv, p[7] * inv);
    *(float4*)(pooledMean + g * DIM + li * 8) = o0;
    *(float4*)(pooledMean + g * DIM + li * 8 + 4) = o1;
  }
}

// ---------------- fused FC head ----------------
__global__ __launch_bounds__(256) void k_fc(const float* __restrict__ pooledMean,
                                            const float* __restrict__ fc_w, const float* __restrict__ fc_b,
                                            const float* __restrict__ reg_w, const float* __restrict__ reg_b,
                                            float* __restrict__ out) {
  __shared__ float sp[128];
  __shared__ float shfc[256];
  __shared__ float red[64];
  int g = blockIdx.x, t = threadIdx.x;
  if (t < 128) sp[t] = pooledMean[g * DIM + t];
  __syncthreads();
  float a = fc_b[t];
  for (int k = 0; k < 128; k++) a += sp[k] * fc_w[k * 256 + t];
  shfc[t] = a;
  __syncthreads();
  if (t < 64) {
    int o = t & 7, seg = t >> 3;
    float r = 0.f;
    for (int j = seg * 32; j < seg * 32 + 32; j++) r += shfc[j] * reg_w[j * 8 + o];
    red[t] = r;
  }
  __syncthreads();
  if (t < 8) {
    float r = reg_b[t];
    for (int s = 0; s < 8; s++) r += red[s * 8 + t];
    out[g * 8 + t] = r;
  }
}

extern "C" void kernel_launch(void* const* d_in, const int* in_sizes, int n_in,
                              void* d_out, int out_size, void* d_ws, size_t ws_size,
                              hipStream_t stream) {
  (void)in_sizes; (void)n_in; (void)out_size; (void)ws_size;
  const float* x = (const float*)d_in[0];
  const int* ei = (const int*)d_in[1];
  const int* src = ei;
  const int* dst = ei + N_EDGES;
  const int* batch = (const int*)d_in[2];
  const float* Wrel[4]  = {(const float*)d_in[3], (const float*)d_in[6], (const float*)d_in[9],  (const float*)d_in[12]};
  const float* Wroot[4] = {(const float*)d_in[4], (const float*)d_in[7], (const float*)d_in[10], (const float*)d_in[13]};
  const float* bias[4]  = {(const float*)d_in[5], (const float*)d_in[8], (const float*)d_in[11], (const float*)d_in[14]};
  const float* fc_w  = (const float*)d_in[15];
  const float* fc_b  = (const float*)d_in[16];
  const float* reg_w = (const float*)d_in[17];
  const float* reg_b = (const float*)d_in[18];
  float* out = (float*)d_out;

  char* ws = (char*)d_ws;
  size_t off = 0;
  auto alloc = [&](size_t b) -> char* {
    char* p = ws + off;
    off = (off + b + 255) & ~(size_t)255;
    return p;
  };
  int* rowptr = (int*)alloc((N_NODES + 1) * 4);
  int* cntmat = (int*)alloc((size_t)NMAT * 4);
  int* tmpB   = (int*)alloc((size_t)NMAT * 4);
  int* bsumB  = (int*)alloc(128 * 4);
  int* base   = (int*)alloc((size_t)NMAT * 4);
  int2* epk   = (int2*)alloc((size_t)N_EDGES * 8);
  int* colws  = (int*)alloc((size_t)N_EDGES * 4);
  int* dcnt   = (int*)alloc((size_t)DMAT * 4);
  int* dtmp   = (int*)alloc((size_t)DMAT * 4);
  int* dbsum  = (int*)alloc(128 * 4);
  int* dbase  = (int*)alloc((size_t)DMAT * 4);
  int* order  = (int*)alloc((size_t)N_NODES * 4);
  int* gptr   = (int*)alloc((N_GRAPHS + 1) * 4);
  unsigned short* wbF = (unsigned short*)alloc((size_t)4 * 32768 * 2);
  unsigned short* h_a = (unsigned short*)alloc((size_t)N_NODES * DIM * 2);
  unsigned short* h_b = (unsigned short*)alloc((size_t)N_NODES * DIM * 2);
  unsigned short* agg = (unsigned short*)alloc((size_t)N_NODES * DIM * 2);
  float* pooled = (float*)alloc((size_t)N_GRAPHS * DIM * 4);

  // bucket CSR build: zero global atomics
  k_bcount<<<NCH, 256, 0, stream>>>(dst, cntmat);
  k_scan1g<<<NMAT / 1024, 256, 0, stream>>>(cntmat, NMAT, tmpB, bsumB);   // 49 blocks
  k_scan2g<<<1, 128, 0, stream>>>(bsumB, NMAT / 1024);
  k_exc<<<(NMAT + 255) / 256, 256, 0, stream>>>(tmpB, bsumB, cntmat, NMAT, base);
  k_bscatter<<<NCH, 256, 0, stream>>>(src, dst, base, epk);
  k_bfinish<<<NBUK, 256, 0, stream>>>(epk, base, rowptr, colws);

  // degree counting sort -> order[] (balance k_agg waves)
  k_dcnt<<<NDB, 256, 0, stream>>>(rowptr, dcnt);
  k_scan1g<<<(DMAT + 1023) / 1024, 256, 0, stream>>>(dcnt, DMAT, dtmp, dbsum);  // 7 blocks
  k_scan2g<<<1, 128, 0, stream>>>(dbsum, (DMAT + 1023) / 1024);
  k_exc<<<(DMAT + 255) / 256, 256, 0, stream>>>(dtmp, dbsum, dcnt, DMAT, dbase);
  k_dscatter<<<NDB, 256, 0, stream>>>(rowptr, dbase, order);

  k_gptr<<<(N_NODES + 255) / 256, 256, 0, stream>>>(batch, gptr);
  k_cvtx<<<(N_NODES * DIM / 4 + 255) / 256, 256, 0, stream>>>(x, h_a);
  k_cvtw<<<(4 * 32768 + 255) / 256, 256, 0, stream>>>(
      Wrel[0], Wroot[0], Wrel[1], Wroot[1], Wrel[2], Wroot[2], Wrel[3], Wroot[3], wbF);

  unsigned short* h_in = h_a;
  unsigned short* h_out = h_b;
  for (int l = 0; l < 4; l++) {
    k_agg<<<(N_NODES + 3) / 4, 256, 0, stream>>>(order, rowptr, colws, h_in, agg);
    k_conv<<<(N_NODES + 127) / 128, 256, 0, stream>>>(
        agg, h_in, wbF + (size_t)l * 32768, bias[l], h_out);
    unsigned short* t2 = h_in; h_in = h_out; h_out = t2;
  }
  // after 4 swaps, final features are in h_in (== h_a)

  k_pool<<<(N_GRAPHS + 3) / 4, 256, 0, stream>>>(h_in, gptr, pooled);
  k_fc<<<N_GRAPHS, 256, 0, stream>>>(pooled, fc_w, fc_b, reg_w, reg_b, out);
}

// Round 9
// 521.517 us; speedup vs baseline: 1.1664x; 1.1664x over previous
//
#include <hip/hip_runtime.h>

#define N_NODES 100000
#define N_EDGES 1600000
#define N_GRAPHS 2048
#define DIM 128

// bucket CSR build params
#define NBUK 196      // ceil(100000/512)
#define BUKSH 9       // bucket = dst >> 9 (512 nodes per bucket)
#define NCH 256       // edge chunks (blocks) in passes A/C
#define EPB 6250      // edges per chunk = N_EDGES / NCH
#define NMAT (NBUK * NCH)  // 50176

typedef short short8v __attribute__((ext_vector_type(8)));
typedef float float4v __attribute__((ext_vector_type(4)));

__device__ __forceinline__ unsigned short f2bf(float f) {
  union { float f; unsigned u; } x; x.f = f;
  unsigned r = x.u + 0x7fffu + ((x.u >> 16) & 1u);
  return (unsigned short)(r >> 16);
}
__device__ __forceinline__ float bfhi2f(unsigned bits) {  // bits already in high half
  union { unsigned u; float f; } x; x.u = bits; return x.f;
}
__device__ __forceinline__ void accum8(float* p, uint4 v) {
  p[0] += bfhi2f(v.x << 16); p[1] += bfhi2f(v.x & 0xffff0000u);
  p[2] += bfhi2f(v.y << 16); p[3] += bfhi2f(v.y & 0xffff0000u);
  p[4] += bfhi2f(v.z << 16); p[5] += bfhi2f(v.z & 0xffff0000u);
  p[6] += bfhi2f(v.w << 16); p[7] += bfhi2f(v.w & 0xffff0000u);
}

// ---------------- bucket CSR build (zero global atomics) ----------------
__global__ __launch_bounds__(256) void k_bcount(const int* __restrict__ dst, int* __restrict__ cntmat) {
  __shared__ int cnt[NBUK];
  int b = blockIdx.x, t = threadIdx.x;
  if (t < NBUK) cnt[t] = 0;
  __syncthreads();
  int e0 = b * EPB;
  for (int j = t; j < EPB; j += 256) atomicAdd(&cnt[dst[e0 + j] >> BUKSH], 1);
  __syncthreads();
  if (t < NBUK) cntmat[t * NCH + b] = cnt[t];
}

// generic scan (chunk = 1024/block)
__global__ __launch_bounds__(256) void k_scan1g(const int* __restrict__ in, int n,
                                                int* __restrict__ tmp, int* __restrict__ bsum) {
  __shared__ int sh[256];
  int b = blockIdx.x, t = threadIdx.x;
  int base = b * 1024 + t * 4;
  int v[4], s = 0;
#pragma unroll
  for (int i = 0; i < 4; i++) { v[i] = (base + i < n) ? in[base + i] : 0; s += v[i]; }
  sh[t] = s;
  __syncthreads();
  for (int off = 1; off < 256; off <<= 1) {
    int x = (t >= off) ? sh[t - off] : 0;
    __syncthreads();
    sh[t] += x;
    __syncthreads();
  }
  int run = sh[t] - s;
#pragma unroll
  for (int i = 0; i < 4; i++) { run += v[i]; if (base + i < n) tmp[base + i] = run; }
  if (t == 255) bsum[b] = sh[255];
}

__global__ void k_scan2g(int* __restrict__ bsum, int nb) {
  __shared__ int sh[128];
  int t = threadIdx.x;
  int v = (t < nb) ? bsum[t] : 0;
  sh[t] = v;
  __syncthreads();
  for (int off = 1; off < 128; off <<= 1) {
    int x = (t >= off) ? sh[t - off] : 0;
    __syncthreads();
    sh[t] += x;
    __syncthreads();
  }
  if (t < nb) bsum[t] = sh[t] - v;  // exclusive
}

__global__ __launch_bounds__(256) void k_exc(const int* __restrict__ tmp, const int* __restrict__ bsum,
                                             const int* __restrict__ in, int n, int* __restrict__ outExc) {
  int i = blockIdx.x * 256 + threadIdx.x;
  if (i < n) outExc[i] = tmp[i] + bsum[i >> 10] - in[i];
}

__global__ __launch_bounds__(256) void k_bscatter(const int* __restrict__ src, const int* __restrict__ dst,
                                                  const int* __restrict__ base, int2* __restrict__ epk) {
  __shared__ int cur[NBUK];
  int b = blockIdx.x, t = threadIdx.x;
  if (t < NBUK) cur[t] = base[t * NCH + b];
  __syncthreads();
  int e0 = b * EPB;
  for (int j = t; j < EPB; j += 256) {
    int s = src[e0 + j], d = dst[e0 + j];
    int pos = atomicAdd(&cur[d >> BUKSH], 1);
    epk[pos] = make_int2(s, d);
  }
}

__global__ __launch_bounds__(256) void k_bfinish(const int2* __restrict__ epk, const int* __restrict__ base,
                                                 int* __restrict__ rowptr, int* __restrict__ col) {
  __shared__ int a[512];
  __shared__ int sh[256];
  int k = blockIdx.x, t = threadIdx.x;
  int bstart = base[k * NCH];
  int bend = (k + 1 < NBUK) ? base[(k + 1) * NCH] : N_EDGES;
  a[t] = 0; a[t + 256] = 0;
  __syncthreads();
  for (int i = bstart + t; i < bend; i += 256) atomicAdd(&a[epk[i].y - (k << BUKSH)], 1);
  __syncthreads();
  int c0 = a[2 * t], c1 = a[2 * t + 1];
  int s = c0 + c1;
  sh[t] = s;
  __syncthreads();
  for (int off = 1; off < 256; off <<= 1) {
    int x = (t >= off) ? sh[t - off] : 0;
    __syncthreads();
    sh[t] += x;
    __syncthreads();
  }
  int excl = sh[t] - s;
  int st0 = bstart + excl;
  int st1 = st0 + c0;
  int g0 = (k << BUKSH) + 2 * t, g1 = g0 + 1;
  if (g0 < N_NODES) rowptr[g0] = st0;
  if (g1 < N_NODES) rowptr[g1] = st1;
  if (k == NBUK - 1 && t == 0) rowptr[N_NODES] = N_EDGES;
  __syncthreads();
  a[2 * t] = st0; a[2 * t + 1] = st1;  // convert to cursors
  __syncthreads();
  for (int i = bstart + t; i < bend; i += 256) {
    int2 e = epk[i];
    int pos = atomicAdd(&a[e.y - (k << BUKSH)], 1);
    col[pos] = e.x;
  }
}

// ---------------- graph boundary pointers (batch is sorted) ----------------
__global__ __launch_bounds__(256) void k_gptr(const int* __restrict__ batch, int* __restrict__ gptr) {
  int i = blockIdx.x * 256 + threadIdx.x;
  if (i >= N_NODES) return;
  int b = batch[i];
  int a = (i == 0) ? -1 : batch[i - 1];
  for (int g = a + 1; g <= b; g++) gptr[g] = i;
  if (i == N_NODES - 1) {
    for (int g = b + 1; g <= N_GRAPHS; g++) gptr[g] = N_NODES;
  }
}

// ---------------- dtype converts ----------------
__global__ __launch_bounds__(256) void k_cvtx(const float* __restrict__ x, unsigned short* __restrict__ h) {
  int i = blockIdx.x * 256 + threadIdx.x;  // over N*DIM/4
  if (i < N_NODES * DIM / 4) {
    float4 v = ((const float4*)x)[i];
    unsigned lo = (unsigned)f2bf(v.x) | ((unsigned)f2bf(v.y) << 16);
    unsigned hi = (unsigned)f2bf(v.z) | ((unsigned)f2bf(v.w) << 16);
    ((uint2*)h)[i] = make_uint2(lo, hi);
  }
}

// Weights -> bf16 MFMA B-fragment order.
__global__ __launch_bounds__(256) void k_cvtw(const float* w0, const float* w1, const float* w2, const float* w3,
                                              const float* w4, const float* w5, const float* w6, const float* w7,
                                              unsigned short* __restrict__ wbF) {
  int i = blockIdx.x * 256 + threadIdx.x;
  if (i < 4 * 8 * 8 * 64 * 8) {
    int j = i & 7, l = (i >> 3) & 63, c = (i >> 9) & 7, kc = (i >> 12) & 7, layer = i >> 15;
    int m = layer * 2 + (kc >> 2);
    const float* w;
    switch (m) {
      case 0: w = w0; break; case 1: w = w1; break; case 2: w = w2; break; case 3: w = w3; break;
      case 4: w = w4; break; case 5: w = w5; break; case 6: w = w6; break; default: w = w7; break;
    }
    int kin = (kc & 3) * 32 + ((l >> 4) * 8) + j;
    int n = c * 16 + (l & 15);
    wbF[i] = f2bf(w[kin * 128 + n]);
  }
}

// ---------------- aggregation: one wave per node, 16 lanes per row, dwordx4 gathers (r7 form) ----------------
__global__ __launch_bounds__(256) void k_agg(const int* __restrict__ rowptr, const int* __restrict__ col,
                                             const unsigned short* __restrict__ hIn,
                                             unsigned short* __restrict__ aggOut) {
  int node = blockIdx.x * 4 + (threadIdx.x >> 6);
  if (node >= N_NODES) return;
  int lane = threadIdx.x & 63;
  int sub = lane >> 4;
  int li = lane & 15;
  int s0 = rowptr[node], s1 = rowptr[node + 1];
  float p[8];
#pragma unroll
  for (int j = 0; j < 8; j++) p[j] = 0.f;

  int e = s0;
  for (; e + 16 <= s1; e += 16) {
    int c0 = col[e + sub];
    int c1 = col[e + 4 + sub];
    int c2 = col[e + 8 + sub];
    int c3 = col[e + 12 + sub];
    uint4 v0 = *(const uint4*)(hIn + (size_t)c0 * DIM + li * 8);
    uint4 v1 = *(const uint4*)(hIn + (size_t)c1 * DIM + li * 8);
    uint4 v2 = *(const uint4*)(hIn + (size_t)c2 * DIM + li * 8);
    uint4 v3 = *(const uint4*)(hIn + (size_t)c3 * DIM + li * 8);
    accum8(p, v0);
    accum8(p, v1);
    accum8(p, v2);
    accum8(p, v3);
  }
  if (e + 8 <= s1) {
    int c0 = col[e + sub];
    int c1 = col[e + 4 + sub];
    uint4 v0 = *(const uint4*)(hIn + (size_t)c0 * DIM + li * 8);
    uint4 v1 = *(const uint4*)(hIn + (size_t)c1 * DIM + li * 8);
    accum8(p, v0);
    accum8(p, v1);
    e += 8;
  }
  if (e + 4 <= s1) {
    int c0 = col[e + sub];
    uint4 v0 = *(const uint4*)(hIn + (size_t)c0 * DIM + li * 8);
    accum8(p, v0);
    e += 4;
  }
  if (e + sub < s1) {
    int c0 = col[e + sub];
    uint4 v0 = *(const uint4*)(hIn + (size_t)c0 * DIM + li * 8);
    accum8(p, v0);
  }

#pragma unroll
  for (int j = 0; j < 8; j++) {
    p[j] += __shfl_xor(p[j], 16, 64);
    p[j] += __shfl_xor(p[j], 32, 64);
  }

  if (sub == 0) {
    uint4 o;
    o.x = (unsigned)f2bf(p[0]) | ((unsigned)f2bf(p[1]) << 16);
    o.y = (unsigned)f2bf(p[2]) | ((unsigned)f2bf(p[3]) << 16);
    o.z = (unsigned)f2bf(p[4]) | ((unsigned)f2bf(p[5]) << 16);
    o.w = (unsigned)f2bf(p[6]) | ((unsigned)f2bf(p[7]) << 16);
    *(uint4*)(aggOut + (size_t)node * DIM + li * 8) = o;
  }
}

// ---------------- fused conv GEMM: h' = relu(agg@Wrel + h@Wroot + b) ----------------
// Two-phase K-split: 32 KB LDS buffer reused (phase 0 = agg/Wrel K 0..127, phase 1 = h/Wroot).
// 4 blocks/CU (vs 2 at 64 KB) doubles the latency-hiding wave pool.
// LDS chunk addr: (g*16 + c)*16 + ((r&15) ^ c), g=row>>4 (0..7), c=k>>3 (0..15) — conflict-free.
__global__ __launch_bounds__(256, 4) void k_conv(const unsigned short* __restrict__ aggB,
                                                 const unsigned short* __restrict__ hIn,
                                                 const unsigned short* __restrict__ wbF,
                                                 const float* __restrict__ bias,
                                                 unsigned short* __restrict__ hOut) {
  __shared__ uint4 As[2048];  // 32 KB: 128 rows x 128 K bf16
  const int t = threadIdx.x;
  const int row0b = blockIdx.x * 128;
  const int wave = t >> 6, lane = t & 63;

  float4v acc[2][8];
#pragma unroll
  for (int r = 0; r < 2; r++)
#pragma unroll
    for (int c = 0; c < 8; c++)
#pragma unroll
      for (int i = 0; i < 4; i++) acc[r][c][i] = 0.f;

#pragma unroll
  for (int phase = 0; phase < 2; phase++) {
    const unsigned short* Asrc = phase ? hIn : aggB;
    // stage 128 rows x 128 K
#pragma unroll
    for (int j = 0; j < 8; j++) {
      int r = j * 16 + (t >> 4);
      int c = t & 15;
      int rsrc = row0b + r; if (rsrc > N_NODES - 1) rsrc = N_NODES - 1;
      uint4 v = *(const uint4*)(Asrc + (size_t)rsrc * DIM + c * 8);
      As[((r >> 4) * 16 + c) * 16 + ((r & 15) ^ c)] = v;
    }
    __syncthreads();

#pragma unroll
    for (int kc = 0; kc < 4; kc++) {
      short8v afr[2];
#pragma unroll
      for (int r = 0; r < 2; r++) {
        int g = wave * 2 + r;
        int c = kc * 4 + (lane >> 4);
        int rr = (lane & 15) ^ c;
        afr[r] = *(const short8v*)&As[(g * 16 + c) * 16 + rr];
      }
      int kcw = phase * 4 + kc;  // wbF chunk: 0-3 Wrel, 4-7 Wroot
#pragma unroll
      for (int c = 0; c < 8; c++) {
        short8v bfr = *(const short8v*)(wbF + (size_t)((kcw * 8 + c) * 64 + lane) * 8);
#pragma unroll
        for (int r = 0; r < 2; r++)
          acc[r][c] = __builtin_amdgcn_mfma_f32_16x16x32_bf16(afr[r], bfr, acc[r][c], 0, 0, 0);
      }
    }
    __syncthreads();  // all waves done reading As before phase-1 overwrite (and before exit)
  }

  // epilogue: D layout col = lane&15, row = (lane>>4)*4 + i
  const int row0 = row0b + wave * 32;
#pragma unroll
  for (int r = 0; r < 2; r++) {
    int rbase = row0 + r * 16 + (lane >> 4) * 4;
#pragma unroll
    for (int c = 0; c < 8; c++) {
      int colidx = c * 16 + (lane & 15);
      float bv = bias[colidx];
#pragma unroll
      for (int i = 0; i < 4; i++) {
        int row = rbase + i;
        if (row < N_NODES) {
          float v = acc[r][c][i] + bv;
          v = v > 0.f ? v : 0.f;
          hOut[row * DIM + colidx] = f2bf(v);
        }
      }
    }
  }
}

// ---------------- pooling: one wave per graph, flat uint4 streaming, no atomics ----------------
__global__ __launch_bounds__(256) void k_pool(const unsigned short* __restrict__ h,
                                              const int* __restrict__ gptr,
                                              float* __restrict__ pooledMean) {
  int g = blockIdx.x * 4 + (threadIdx.x >> 6);
  if (g >= N_GRAPHS) return;
  int lane = threadIdx.x & 63;
  int li = lane & 15;
  int s0 = gptr[g], s1 = gptr[g + 1];
  float p[8];
#pragma unroll
  for (int j = 0; j < 8; j++) p[j] = 0.f;
  int f1 = s1 * 16;
  for (int f = s0 * 16 + lane; f < f1; f += 64) {
    uint4 v = ((const uint4*)h)[f];
    accum8(p, v);
  }
#pragma unroll
  for (int j = 0; j < 8; j++) {
    p[j] += __shfl_xor(p[j], 16, 64);
    p[j] += __shfl_xor(p[j], 32, 64);
  }
  float inv = (s1 > s0) ? 1.f / (float)(s1 - s0) : 0.f;
  if (lane < 16) {
    float4 o0 = make_float4(p[0] * inv, p[1] * inv, p[2] * inv, p[3] * inv);
    float4 o1 = make_float4(p[4] * inv, p[5] * inv, p[6] * inv, p[7] * inv);
    *(float4*)(pooledMean + g * DIM + li * 8) = o0;
    *(float4*)(pooledMean + g * DIM + li * 8 + 4) = o1;
  }
}

// ---------------- fused FC head ----------------
__global__ __launch_bounds__(256) void k_fc(const float* __restrict__ pooledMean,
                                            const float* __restrict__ fc_w, const float* __restrict__ fc_b,
                                            const float* __restrict__ reg_w, const float* __restrict__ reg_b,
                                            float* __restrict__ out) {
  __shared__ float sp[128];
  __shared__ float shfc[256];
  __shared__ float red[64];
  int g = blockIdx.x, t = threadIdx.x;
  if (t < 128) sp[t] = pooledMean[g * DIM + t];
  __syncthreads();
  float a = fc_b[t];
  for (int k = 0; k < 128; k++) a += sp[k] * fc_w[k * 256 + t];
  shfc[t] = a;
  __syncthreads();
  if (t < 64) {
    int o = t & 7, seg = t >> 3;
    float r = 0.f;
    for (int j = seg * 32; j < seg * 32 + 32; j++) r += shfc[j] * reg_w[j * 8 + o];
    red[t] = r;
  }
  __syncthreads();
  if (t < 8) {
    float r = reg_b[t];
    for (int s = 0; s < 8; s++) r += red[s * 8 + t];
    out[g * 8 + t] = r;
  }
}

extern "C" void kernel_launch(void* const* d_in, const int* in_sizes, int n_in,
                              void* d_out, int out_size, void* d_ws, size_t ws_size,
                              hipStream_t stream) {
  (void)in_sizes; (void)n_in; (void)out_size; (void)ws_size;
  const float* x = (const float*)d_in[0];
  const int* ei = (const int*)d_in[1];
  const int* src = ei;
  const int* dst = ei + N_EDGES;
  const int* batch = (const int*)d_in[2];
  const float* Wrel[4]  = {(const float*)d_in[3], (const float*)d_in[6], (const float*)d_in[9],  (const float*)d_in[12]};
  const float* Wroot[4] = {(const float*)d_in[4], (const float*)d_in[7], (const float*)d_in[10], (const float*)d_in[13]};
  const float* bias[4]  = {(const float*)d_in[5], (const float*)d_in[8], (const float*)d_in[11], (const float*)d_in[14]};
  const float* fc_w  = (const float*)d_in[15];
  const float* fc_b  = (const float*)d_in[16];
  const float* reg_w = (const float*)d_in[17];
  const float* reg_b = (const float*)d_in[18];
  float* out = (float*)d_out;

  char* ws = (char*)d_ws;
  size_t off = 0;
  auto alloc = [&](size_t b) -> char* {
    char* p = ws + off;
    off = (off + b + 255) & ~(size_t)255;
    return p;
  };
  int* rowptr = (int*)alloc((N_NODES + 1) * 4);
  int* cntmat = (int*)alloc((size_t)NMAT * 4);
  int* tmpB   = (int*)alloc((size_t)NMAT * 4);
  int* bsumB  = (int*)alloc(128 * 4);
  int* base   = (int*)alloc((size_t)NMAT * 4);
  int2* epk   = (int2*)alloc((size_t)N_EDGES * 8);
  int* colws  = (int*)alloc((size_t)N_EDGES * 4);
  int* gptr   = (int*)alloc((N_GRAPHS + 1) * 4);
  unsigned short* wbF = (unsigned short*)alloc((size_t)4 * 32768 * 2);
  unsigned short* h_a = (unsigned short*)alloc((size_t)N_NODES * DIM * 2);
  unsigned short* h_b = (unsigned short*)alloc((size_t)N_NODES * DIM * 2);
  unsigned short* agg = (unsigned short*)alloc((size_t)N_NODES * DIM * 2);
  float* pooled = (float*)alloc((size_t)N_GRAPHS * DIM * 4);

  // bucket CSR build: zero global atomics
  k_bcount<<<NCH, 256, 0, stream>>>(dst, cntmat);
  k_scan1g<<<NMAT / 1024, 256, 0, stream>>>(cntmat, NMAT, tmpB, bsumB);   // 49 blocks
  k_scan2g<<<1, 128, 0, stream>>>(bsumB, NMAT / 1024);
  k_exc<<<(NMAT + 255) / 256, 256, 0, stream>>>(tmpB, bsumB, cntmat, NMAT, base);
  k_bscatter<<<NCH, 256, 0, stream>>>(src, dst, base, epk);
  k_bfinish<<<NBUK, 256, 0, stream>>>(epk, base, rowptr, colws);

  k_gptr<<<(N_NODES + 255) / 256, 256, 0, stream>>>(batch, gptr);
  k_cvtx<<<(N_NODES * DIM / 4 + 255) / 256, 256, 0, stream>>>(x, h_a);
  k_cvtw<<<(4 * 32768 + 255) / 256, 256, 0, stream>>>(
      Wrel[0], Wroot[0], Wrel[1], Wroot[1], Wrel[2], Wroot[2], Wrel[3], Wroot[3], wbF);

  unsigned short* h_in = h_a;
  unsigned short* h_out = h_b;
  for (int l = 0; l < 4; l++) {
    k_agg<<<(N_NODES + 3) / 4, 256, 0, stream>>>(rowptr, colws, h_in, agg);
    k_conv<<<(N_NODES + 127) / 128, 256, 0, stream>>>(
        agg, h_in, wbF + (size_t)l * 32768, bias[l], h_out);
    unsigned short* t2 = h_in; h_in = h_out; h_out = t2;
  }
  // after 4 swaps, final features are in h_in (== h_a)

  k_pool<<<(N_GRAPHS + 3) / 4, 256, 0, stream>>>(h_in, gptr, pooled);
  k_fc<<<N_GRAPHS, 256, 0, stream>>>(pooled, fc_w, fc_b, reg_w, reg_b, out);
}